// Round 8
// baseline (834.221 us; speedup 1.0000x reference)
//
#include <hip/hip_runtime.h>

using u16 = unsigned short;

typedef __bf16 bf16x8 __attribute__((ext_vector_type(8)));
typedef u16    u16x8  __attribute__((ext_vector_type(8)));
typedef float  f32x4  __attribute__((ext_vector_type(4)));

__device__ __forceinline__ float b2f(u16 u) {
    union { unsigned int i; float f; } c; c.i = ((unsigned int)u) << 16; return c.f;
}
__device__ __forceinline__ u16 f2b(float f) {
    union { float f; unsigned int i; } c; c.f = f;
    unsigned int i = c.i;
    return (u16)((i + 0x7FFFu + ((i >> 16) & 1u)) >> 16);
}

#define AS1 __attribute__((address_space(1)))
#define AS3 __attribute__((address_space(3)))
__device__ __forceinline__ void glds16(const u16* g, u16* l) {
    __builtin_amdgcn_global_load_lds((const AS1 void*)(const void*)g,
                                     (AS3 void*)(void*)l, 16, 0, 0);
}

// ---------------------------------------------------------------------------
// Batched transpose + convert f32 -> bf16: in[b][R][C] f32 -> out[b][C][R] bf16
// ---------------------------------------------------------------------------
__global__ void btrans_f2b(const float* __restrict__ in, u16* __restrict__ out, int R, int C) {
    __shared__ u16 tile[32][33];
    const int c0 = blockIdx.x * 32, r0 = blockIdx.y * 32;
    const size_t base = (size_t)blockIdx.z * R * C;
    const int tx = threadIdx.x, ty = threadIdx.y;
    #pragma unroll
    for (int i = ty; i < 32; i += 8) {
        int r = r0 + i, c = c0 + tx;
        tile[i][tx] = (r < R && c < C) ? f2b(in[base + (size_t)r * C + c]) : (u16)0;
    }
    __syncthreads();
    #pragma unroll
    for (int i = ty; i < 32; i += 8) {
        int c = c0 + i, r = r0 + tx;
        if (c < C && r < R) out[base + (size_t)c * R + r] = tile[tx][i];
    }
}

// Batched transpose + convert bf16 -> f32: in[b][R][C] bf16 -> out[b][C][R] f32
__global__ void btrans_b2f(const u16* __restrict__ in, float* __restrict__ out, int R, int C) {
    __shared__ u16 tile[32][33];
    const int c0 = blockIdx.x * 32, r0 = blockIdx.y * 32;
    const size_t base = (size_t)blockIdx.z * R * C;
    const int tx = threadIdx.x, ty = threadIdx.y;
    #pragma unroll
    for (int i = ty; i < 32; i += 8) {
        int r = r0 + i, c = c0 + tx;
        tile[i][tx] = (r < R && c < C) ? in[base + (size_t)r * C + c] : (u16)0;
    }
    __syncthreads();
    #pragma unroll
    for (int i = ty; i < 32; i += 8) {
        int c = c0 + i, r = r0 + tx;
        if (c < C && r < R) out[base + (size_t)c * R + r] = b2f(tile[tx][i]);
    }
}

// ---------------------------------------------------------------------------
// GEMM: C[M,N] = epilogue(A[M,K] @ BT[N,K]^T + bias)   (A,BT,C bf16)
// 128x128 tile, BK=32, 4 waves, single-barrier double-buffered K-loop,
// XOR-swizzled LDS. Used for QKV (EPI0) and proj (EPI1).
// ---------------------------------------------------------------------------
template<int EPI>
__launch_bounds__(256)
__global__ void gemm_bt(const u16* __restrict__ A, const u16* __restrict__ BT,
                        const float* __restrict__ bias, u16* __restrict__ C,
                        int M, int N, int K, int row0,
                        const u16* __restrict__ R0,
                        const float* __restrict__ g, const float* __restrict__ be,
                        const float* __restrict__ rmv, const float* __restrict__ rvv,
                        const float* __restrict__ alpha,
                        const float* __restrict__ saw, const float* __restrict__ sab) {
    __shared__ __align__(16) u16 ALds[2][128 * 32];
    __shared__ __align__(16) u16 BLds[2][128 * 32];
    const int tid  = threadIdx.x;
    const int wave = tid >> 6, lane = tid & 63;
    const int wm = wave >> 1, wn = wave & 1;
    const int quad = lane >> 4, l16 = lane & 15;
    const int m0 = blockIdx.y * 128, n0 = blockIdx.x * 128;

    const int srow = lane >> 2;
    const int scol = (((lane & 3) ^ ((srow >> 1) & 3)) * 8);
    const size_t aoff0 = (size_t)(m0 + wave * 32 + srow) * K + scol;
    const size_t aoff1 = aoff0 + (size_t)16 * K;
    const size_t boff0 = (size_t)(n0 + wave * 32 + srow) * K + scol;
    const size_t boff1 = boff0 + (size_t)16 * K;
    u16* aD0[2] = { &ALds[0][(wave * 2    ) * 512], &ALds[1][(wave * 2    ) * 512] };
    u16* aD1[2] = { &ALds[0][(wave * 2 + 1) * 512], &ALds[1][(wave * 2 + 1) * 512] };
    u16* bD0[2] = { &BLds[0][(wave * 2    ) * 512], &BLds[1][(wave * 2    ) * 512] };
    u16* bD1[2] = { &BLds[0][(wave * 2 + 1) * 512], &BLds[1][(wave * 2 + 1) * 512] };

    const int cfrag = (quad ^ ((l16 >> 1) & 3)) * 8;

    f32x4 acc[4][4] = {};
    const int niter = K >> 5;

    glds16(A  + aoff0, aD0[0]);
    glds16(A  + aoff1, aD1[0]);
    glds16(BT + boff0, bD0[0]);
    glds16(BT + boff1, bD1[0]);

    for (int kt = 0; kt < niter; kt++) {
        const int cur = kt & 1, nxt = cur ^ 1;
        __syncthreads();
        if (kt + 1 < niter) {
            const size_t kn = (size_t)(kt + 1) << 5;
            glds16(A  + aoff0 + kn, aD0[nxt]);
            glds16(A  + aoff1 + kn, aD1[nxt]);
            glds16(BT + boff0 + kn, bD0[nxt]);
            glds16(BT + boff1 + kn, bD1[nxt]);
        }
        bf16x8 af[4], bfr[4];
        #pragma unroll
        for (int i = 0; i < 4; i++)
            af[i] = *(const bf16x8*)&ALds[cur][(wm * 64 + i * 16 + l16) * 32 + cfrag];
        #pragma unroll
        for (int j = 0; j < 4; j++)
            bfr[j] = *(const bf16x8*)&BLds[cur][(wn * 64 + j * 16 + l16) * 32 + cfrag];
        #pragma unroll
        for (int i = 0; i < 4; i++)
            #pragma unroll
            for (int j = 0; j < 4; j++)
                acc[i][j] = __builtin_amdgcn_mfma_f32_16x16x32_bf16(af[i], bfr[j], acc[i][j], 0, 0, 0);
    }

    float alphav = 0.f;
    if (EPI == 1) alphav = alpha[0];

    #pragma unroll
    for (int i = 0; i < 4; i++) {
        const int rowb = m0 + wm * 64 + i * 16 + quad * 4;
        #pragma unroll
        for (int r = 0; r < 4; r++) {
            const int row = rowb + r;
            float swv = 0.f, sbv = 0.f;
            if (EPI == 2) { int bidx = (row0 + row) / 196; swv = saw[bidx]; sbv = sab[bidx]; }
            #pragma unroll
            for (int j = 0; j < 4; j++) {
                const int col = n0 + wn * 64 + j * 16 + l16;
                float v = acc[i][j][r] + bias[col];
                const size_t off = (size_t)row * N + col;
                if (EPI == 0) {
                    C[off] = f2b(v);
                } else if (EPI == 1) {
                    float x  = v + b2f(R0[off]);
                    float sc = g[col] * rsqrtf(rvv[col] + 1e-5f);
                    float t  = (x - rmv[col]) * sc + be[col] + alphav * x;
                    C[off]  = f2b(t);
                } else {
                    float w   = swv * v + sbv;
                    float out = v / (1.f + __expf(-w * v));
                    C[off] = f2b(out);
                }
            }
        }
    }
}

// ---------------------------------------------------------------------------
// Fused FFN: per block a 64-row stripe of t1.
//   for each of 8 chunks (256 h-cols): h = SiLU_spatial(t1 @ W1[:,ch] + b1)
//   kept in LDS; out_acc += h @ W2[ch,:]. Epilogue: RepBN2(t1 + out + b2) -> t2.
// 4 waves (2x2): GEMM1 wave-tile 32x128 (hacc[2][8]), GEMM2 32x128 (acc[2][8]).
// t1 A-frags preloaded from global (64 VGPR, reused by all chunks).
// LDS: Hl 64x256 (32KB, swizzled) + Wl dbuf 2x(256x32) (32KB) = 64KB.
// ---------------------------------------------------------------------------
__launch_bounds__(256, 2)
__global__ void fused_ffn(const u16* __restrict__ t1, const u16* __restrict__ W1T,
                          const float* __restrict__ b1,
                          const float* __restrict__ saw, const float* __restrict__ sab,
                          const u16* __restrict__ W2T, const float* __restrict__ b2,
                          const float* __restrict__ g, const float* __restrict__ be,
                          const float* __restrict__ rmv, const float* __restrict__ rvv,
                          const float* __restrict__ alpha,
                          u16* __restrict__ out) {
    __shared__ __align__(16) u16 Hl[64 * 256];      // 32 KB
    __shared__ __align__(16) u16 Wl[2][256 * 32];   // 32 KB
    const int tid  = threadIdx.x;
    const int wave = tid >> 6, lane = tid & 63;
    const int wm = wave >> 1, wn = wave & 1;
    const int quad = lane >> 4, l16 = lane & 15;
    const int m0 = blockIdx.x * 64;

    const int srow = lane >> 2;                                // 0..15
    const int scol = (((lane & 3) ^ ((srow >> 1) & 3)) * 8);   // swizzled k-chunk
    const int cfrag = (quad ^ ((l16 >> 1) & 3)) * 8;

    // preload t1 A-frags: afrag[i][kk], row = m0 + wm*32 + i*16 + l16, k = kk*32+quad*8
    bf16x8 afrag[2][8];
    #pragma unroll
    for (int i = 0; i < 2; i++) {
        const size_t rbase = (size_t)(m0 + wm * 32 + i * 16 + l16) * 256 + quad * 8;
        #pragma unroll
        for (int kk = 0; kk < 8; kk++)
            afrag[i][kk] = *(const bf16x8*)&t1[rbase + kk * 32];
    }

    f32x4 acc[2][8] = {};   // persistent out accumulator (rows 32, cols 128 per wave)

    for (int c = 0; c < 8; c++) {
        const int hc0 = c * 256;

        // ---- GEMM1: hacc = t1_stripe @ W1T[hc0..hc0+255][:]  (K=256, 8 iters) ----
        f32x4 hacc[2][8] = {};
        {
            const u16* base = W1T + (size_t)hc0 * 256;
            // prologue stage kk=0 -> buf0 (4 panels of 16 rows per wave)
            #pragma unroll
            for (int pp = 0; pp < 4; pp++)
                glds16(base + (size_t)(wave * 64 + pp * 16 + srow) * 256 + scol,
                       &Wl[0][(wave * 64 + pp * 16) * 32]);
            #pragma unroll
            for (int kk = 0; kk < 8; kk++) {
                const int cur = kk & 1, nxt = cur ^ 1;
                __syncthreads();
                if (kk + 1 < 8) {
                    #pragma unroll
                    for (int pp = 0; pp < 4; pp++)
                        glds16(base + (size_t)(wave * 64 + pp * 16 + srow) * 256 + (kk + 1) * 32 + scol,
                               &Wl[nxt][(wave * 64 + pp * 16) * 32]);
                }
                bf16x8 bfr[8];
                #pragma unroll
                for (int j = 0; j < 8; j++)
                    bfr[j] = *(const bf16x8*)&Wl[cur][(wn * 128 + j * 16 + l16) * 32 + cfrag];
                #pragma unroll
                for (int i = 0; i < 2; i++)
                    #pragma unroll
                    for (int j = 0; j < 8; j++)
                        hacc[i][j] = __builtin_amdgcn_mfma_f32_16x16x32_bf16(afrag[i][kk], bfr[j], hacc[i][j], 0, 0, 0);
            }
        }

        // ---- SiLU_spatial + write h chunk to Hl (swizzled) ----
        #pragma unroll
        for (int i = 0; i < 2; i++) {
            #pragma unroll
            for (int r = 0; r < 4; r++) {
                const int row = wm * 32 + i * 16 + quad * 4 + r;
                const int bidx = (m0 + row) / 196;
                const float swv = saw[bidx], sbv = sab[bidx];
                const int rsw = (row >> 1) & 3;
                #pragma unroll
                for (int j = 0; j < 8; j++) {
                    const int col = wn * 128 + j * 16 + l16;
                    float v = hacc[i][j][r] + b1[hc0 + col];
                    float w = swv * v + sbv;
                    float hv = v / (1.f + __expf(-w * v));
                    const int gch = col >> 3;
                    const int p = (gch & ~3) | ((gch & 3) ^ rsw);
                    Hl[row * 256 + p * 8 + (col & 7)] = f2b(hv);
                }
            }
        }
        __syncthreads();   // (a) Hl complete + all GEMM1 Wl reads done

        // ---- GEMM2 partial: acc += Hl @ W2T[:, hc0..hc0+255]  (K=256, 8 iters) ----
        {
            // prologue stage kk=0 -> buf0
            #pragma unroll
            for (int pp = 0; pp < 4; pp++)
                glds16(W2T + (size_t)(wave * 64 + pp * 16 + srow) * 2048 + hc0 + scol,
                       &Wl[0][(wave * 64 + pp * 16) * 32]);
            #pragma unroll
            for (int kk = 0; kk < 8; kk++) {
                const int cur = kk & 1, nxt = cur ^ 1;
                __syncthreads();
                if (kk + 1 < 8) {
                    #pragma unroll
                    for (int pp = 0; pp < 4; pp++)
                        glds16(W2T + (size_t)(wave * 64 + pp * 16 + srow) * 2048 + hc0 + (kk + 1) * 32 + scol,
                               &Wl[nxt][(wave * 64 + pp * 16) * 32]);
                }
                bf16x8 ah[2], bfr[8];
                #pragma unroll
                for (int i = 0; i < 2; i++) {
                    const int row = wm * 32 + i * 16 + l16;
                    const int p = kk * 4 + (quad ^ ((l16 >> 1) & 3));
                    ah[i] = *(const bf16x8*)&Hl[row * 256 + p * 8];
                }
                #pragma unroll
                for (int j = 0; j < 8; j++)
                    bfr[j] = *(const bf16x8*)&Wl[cur][(wn * 128 + j * 16 + l16) * 32 + cfrag];
                #pragma unroll
                for (int i = 0; i < 2; i++)
                    #pragma unroll
                    for (int j = 0; j < 8; j++)
                        acc[i][j] = __builtin_amdgcn_mfma_f32_16x16x32_bf16(ah[i], bfr[j], acc[i][j], 0, 0, 0);
            }
        }
        __syncthreads();   // (c) all GEMM2 Wl/Hl reads done before next chunk restages
    }

    // ---- epilogue: RepBN2(t1 + acc + b2) -> out ----
    const float alphav = alpha[0];
    #pragma unroll
    for (int i = 0; i < 2; i++) {
        #pragma unroll
        for (int r = 0; r < 4; r++) {
            const int row = m0 + wm * 32 + i * 16 + quad * 4 + r;
            #pragma unroll
            for (int j = 0; j < 8; j++) {
                const int col = wn * 128 + j * 16 + l16;
                const size_t off = (size_t)row * 256 + col;
                float v = acc[i][j][r] + b2[col];
                float x = v + b2f(t1[off]);
                float sc = g[col] * rsqrtf(rvv[col] + 1e-5f);
                float t = (x - rmv[col]) * sc + be[col] + alphav * x;
                out[off] = f2b(t);
            }
        }
    }
}

// ---------------------------------------------------------------------------
// MFMA flash attention: one block per (local b, h), 4 waves. (unchanged R5)
// ---------------------------------------------------------------------------
__launch_bounds__(256)
__global__ void attn_kernel(const u16* __restrict__ qkv, u16* __restrict__ o) {
    __shared__ __align__(16) u16 Kb[224 * 32];
    __shared__ __align__(16) u16 Vt[32 * 232];
    __shared__ __align__(16) u16 Pl[4][16 * 232];
    const int tid  = threadIdx.x;
    const int wave = tid >> 6, lane = tid & 63;
    const int quad = lane >> 4, l16 = lane & 15;
    const int b = blockIdx.x >> 3, h = blockIdx.x & 7;
    const u16* qg = qkv + (size_t)b * 196 * 768 + h * 32;
    const float scale = 0.17677669529663687f;

    for (int idx = tid; idx < 896; idx += 256) {
        int row = idx >> 2, dp = (idx & 3) * 8;
        u16x8 kv = {};
        if (row < 196) kv = *(const u16x8*)&qg[(size_t)row * 768 + 256 + dp];
        *(u16x8*)&Kb[row * 32 + dp] = kv;
    }
    for (int idx = tid; idx < 224 * 32; idx += 256) {
        int row = idx >> 5, d = idx & 31;
        Vt[d * 232 + row] = (row < 196) ? qg[(size_t)row * 768 + 512 + d] : (u16)0;
    }
    for (int c = lane; c < 16 * 24; c += 64) {
        int m = c / 24, cc = 208 + (c % 24);
        Pl[wave][m * 232 + cc] = 0;
    }
    __syncthreads();

    for (int t = wave; t < 13; t += 4) {
        const int m0 = t * 16;
        bf16x8 aq = {};
        const int qrow = m0 + l16;
        if (qrow < 196) aq = *(const bf16x8*)&qg[(size_t)qrow * 768 + quad * 8];

        f32x4 s[13];
        #pragma unroll
        for (int ct = 0; ct < 13; ct++) {
            bf16x8 bk = *(const bf16x8*)&Kb[(ct * 16 + l16) * 32 + quad * 8];
            s[ct] = __builtin_amdgcn_mfma_f32_16x16x32_bf16(aq, bk, (f32x4){0.f, 0.f, 0.f, 0.f}, 0, 0, 0);
        }
        if (l16 >= 4) {
            #pragma unroll
            for (int r = 0; r < 4; r++) s[12][r] = -1e30f;
        }
        float mx[4] = {-1e30f, -1e30f, -1e30f, -1e30f};
        #pragma unroll
        for (int ct = 0; ct < 13; ct++)
            #pragma unroll
            for (int r = 0; r < 4; r++) mx[r] = fmaxf(mx[r], s[ct][r]);
        #pragma unroll
        for (int off = 1; off < 16; off <<= 1)
            #pragma unroll
            for (int r = 0; r < 4; r++) mx[r] = fmaxf(mx[r], __shfl_xor(mx[r], off, 64));
        float sum[4] = {0.f, 0.f, 0.f, 0.f};
        #pragma unroll
        for (int ct = 0; ct < 13; ct++) {
            #pragma unroll
            for (int r = 0; r < 4; r++) {
                float p = __expf((s[ct][r] - mx[r]) * scale);
                sum[r] += p;
                Pl[wave][(quad * 4 + r) * 232 + ct * 16 + l16] = f2b(p);
            }
        }
        #pragma unroll
        for (int off = 1; off < 16; off <<= 1)
            #pragma unroll
            for (int r = 0; r < 4; r++) sum[r] += __shfl_xor(sum[r], off, 64);
        float inv[4];
        #pragma unroll
        for (int r = 0; r < 4; r++) inv[r] = 1.f / sum[r];

        #pragma unroll
        for (int nt = 0; nt < 2; nt++) {
            f32x4 ao = {0.f, 0.f, 0.f, 0.f};
            #pragma unroll
            for (int kc = 0; kc < 7; kc++) {
                bf16x8 ap = *(const bf16x8*)&Pl[wave][l16 * 232 + kc * 32 + quad * 8];
                bf16x8 bv = *(const bf16x8*)&Vt[(nt * 16 + l16) * 232 + kc * 32 + quad * 8];
                ao = __builtin_amdgcn_mfma_f32_16x16x32_bf16(ap, bv, ao, 0, 0, 0);
            }
            #pragma unroll
            for (int r = 0; r < 4; r++) {
                const int gm = m0 + quad * 4 + r;
                if (gm < 196)
                    o[((size_t)b * 196 + gm) * 256 + h * 32 + nt * 16 + l16] = f2b(ao[r] * inv[r]);
            }
        }
    }
}

// ---------------------------------------------------------------------------
extern "C" void kernel_launch(void* const* d_in, const int* in_sizes, int n_in,
                              void* d_out, int out_size, void* d_ws, size_t ws_size,
                              hipStream_t stream) {
    const float* x      = (const float*)d_in[0];
    const float* Wqkv   = (const float*)d_in[1];
    const float* bqkv   = (const float*)d_in[2];
    const float* Wproj  = (const float*)d_in[3];
    const float* bproj  = (const float*)d_in[4];
    const float* W1     = (const float*)d_in[5];
    const float* b1     = (const float*)d_in[6];
    const float* W2     = (const float*)d_in[7];
    const float* b2     = (const float*)d_in[8];
    const float* saw    = (const float*)d_in[9];
    const float* sab    = (const float*)d_in[10];
    const float* alpha1 = (const float*)d_in[11];
    const float* g1     = (const float*)d_in[12];
    const float* be1    = (const float*)d_in[13];
    const float* rm1    = (const float*)d_in[14];
    const float* rv1    = (const float*)d_in[15];
    const float* alpha2 = (const float*)d_in[16];
    const float* g2     = (const float*)d_in[17];
    const float* be2    = (const float*)d_in[18];
    const float* rm2    = (const float*)d_in[19];
    const float* rv2    = (const float*)d_in[20];

    const int B = 256, Cc = 256, Np = 196, CM = 2048;
    const int M = B * Np; // 50176

    auto al = [](size_t s) { return (s + 255) & ~(size_t)255; };
    char* ws = (char*)d_ws;
    const size_t o_t0  = 0;
    const size_t o_t1  = o_t0 + al((size_t)M * Cc * 2);
    const size_t o_wq  = o_t1 + al((size_t)M * Cc * 2);
    const size_t o_wp  = o_wq + al((size_t)768 * Cc * 2);
    const size_t o_w1  = o_wp + al((size_t)Cc * Cc * 2);
    const size_t o_w2  = o_w1 + al((size_t)Cc * CM * 2);
    const size_t o_scr = o_w2 + al((size_t)CM * Cc * 2);
    const size_t S = (ws_size > o_scr) ? ws_size - o_scr : 0;

    u16* t0     = (u16*)(ws + o_t0);
    u16* t1b    = (u16*)(ws + o_t1);
    u16* WqkvT  = (u16*)(ws + o_wq);
    u16* WprojT = (u16*)(ws + o_wp);
    u16* W1T    = (u16*)(ws + o_w1);
    u16* W2T    = (u16*)(ws + o_w2);
    u16* scr    = (u16*)(ws + o_scr);
    u16* t2     = t0;            // alias: t0 dead after proj epilogue
    u16* obuf   = (u16*)d_out;   // bf16 scratch in f32 d_out; fully rewritten at end
    float* out  = (float*)d_out;

    int nq = 1; while (nq < 8 && ((size_t)(M / nq) * 768 * 2) > S) nq *= 2;
    const int Mq = M / nq, Bq = B / nq;

    dim3 tb(32, 8, 1);
    btrans_f2b<<<dim3((Np + 31) / 32, (Cc + 31) / 32, B), tb, 0, stream>>>(x, t0, Cc, Np);
    btrans_f2b<<<dim3(768 / 32, Cc / 32, 1), tb, 0, stream>>>(Wqkv,  WqkvT,  Cc, 768);
    btrans_f2b<<<dim3(Cc  / 32, Cc / 32, 1), tb, 0, stream>>>(Wproj, WprojT, Cc, Cc);
    btrans_f2b<<<dim3(CM  / 32, Cc / 32, 1), tb, 0, stream>>>(W1,    W1T,    Cc, CM);
    btrans_f2b<<<dim3(Cc  / 32, CM / 32, 1), tb, 0, stream>>>(W2,    W2T,    CM, Cc);

    for (int c = 0; c < nq; ++c) {
        gemm_bt<0><<<dim3(768 / 128, Mq / 128), 256, 0, stream>>>(
            t0 + (size_t)c * Mq * Cc, WqkvT, bqkv, scr, Mq, 768, Cc, 0,
            nullptr, nullptr, nullptr, nullptr, nullptr, nullptr, nullptr, nullptr);
        attn_kernel<<<dim3(Bq * 8), 256, 0, stream>>>(scr, obuf + (size_t)c * Mq * Cc);
    }

    // t1 = RepBN1(t0 + obuf @ Wproj + bproj)
    gemm_bt<1><<<dim3(Cc / 128, M / 128), 256, 0, stream>>>(
        obuf, WprojT, bproj, t1b, M, Cc, Cc, 0,
        t0, g1, be1, rm1, rv1, alpha1, nullptr, nullptr);

    // fused FFN: t2 = RepBN2(t1 + SiLU_spatial(t1@W1+b1)@W2 + b2)
    fused_ffn<<<dim3(M / 64), 256, 0, stream>>>(
        t1b, W1T, b1, saw, sab, W2T, b2, g2, be2, rm2, rv2, alpha2, t2);

    btrans_b2f<<<dim3((Cc + 31) / 32, (Np + 31) / 32, B), tb, 0, stream>>>(t2, out, Np, Cc);
}